// Round 7
// baseline (381.688 us; speedup 1.0000x reference)
//
#include <hip/hip_runtime.h>
#include <hip/hip_bf16.h>
#include <stdint.h>

// Answer_Decoder: B=64, T=24, H=512, V=32000, E=256. All I/O float32.
// Attention is dead code (softmax over size-1 axis => ctx == cat(q,img)).
// Pipeline:
//   0) cvt Wih0 f32->bf16; pack recurrent weights bf16 per-block
//   1) build_x: X[1536][1280] bf16
//   2) G0 = X @ W_ih0^T + b_ih0 + b_hh0 (f32, gemm128)
//   3) fused_wave: ONE persistent kernel, 248 blocks:
//        blocks 0..95   = LSTM (t,layer) wavefront (32 j-slice blocks/layer);
//        blocks 96..247 = fc workers consuming h2[t] as flags appear.
//      Cross-XCD handoff via sc0 sc1 (L3-coherent) h stores/loads,
//      single-writer RELAXED agent flags. W persistent in LDS (XOR-swizzled).
//      fc: h2 @ fc_W^T + fc_b -> out[b][t][v], fcW converted f32->bf16 in-staging.

typedef short bf16x8 __attribute__((ext_vector_type(8)));
typedef float f32x4 __attribute__((ext_vector_type(4)));

#define NLSTM 96
#define FCB   152
#define NTILE_N 250          // 32000/128
#define NTILE   3000         // 12 m-tiles * 250

__device__ __forceinline__ unsigned short f2b(float f) {
    uint32_t u = __builtin_bit_cast(uint32_t, f);
    uint32_t r = u + 0x7FFFu + ((u >> 16) & 1u);
    return (unsigned short)(r >> 16);
}
__device__ __forceinline__ float sigmoidf(float x) {
    return 1.0f / (1.0f + expf(-x));
}

// ---------------- f32 -> bf16 convert ----------------
__global__ __launch_bounds__(256) void cvt_bf16(
    const float* __restrict__ src, unsigned short* __restrict__ dst, int n4)
{
    int i = blockIdx.x * 256 + threadIdx.x;
    if (i >= n4) return;
    f32x4 v = *(const f32x4*)&src[i * 4];
    unsigned short o[4];
    #pragma unroll
    for (int j = 0; j < 4; ++j) o[j] = f2b(v[j]);
    *(uint64_t*)&dst[i * 4] = *(uint64_t*)o;
}

// ---------------- pack recurrent weights (bf16, per-block contiguous) -------
// Wpk layout: l0 [32][64][512] ; l1 [32][64][1024] ; l2 [32][64][1024]
// block row r in [0,64): gate q=r>>4, jj=r&15; source gate-row = q*512+lbid*16+jj
__global__ __launch_bounds__(128) void pack_w(
    const float* __restrict__ Whh0,
    const float* __restrict__ Wih1, const float* __restrict__ Whh1,
    const float* __restrict__ Wih2, const float* __restrict__ Whh2,
    unsigned short* __restrict__ Wpk)
{
    int gid = blockIdx.x;                 // 3*32*64 = 6144
    int layer = gid / (32 * 64);
    int rem = gid % (32 * 64);
    int lbid = rem >> 6, r = rem & 63;
    int q = r >> 4, jj = r & 15;
    int grow = q * 512 + lbid * 16 + jj;
    int K = (layer == 0) ? 512 : 1024;
    size_t wbase = (layer == 0) ? 0
                 : (layer == 1) ? (size_t)32 * 64 * 512
                                : (size_t)32 * 64 * 512 + (size_t)32 * 64 * 1024;
    unsigned short* dst = Wpk + wbase + ((size_t)lbid * 64 + r) * K;
    const float *s0, *s1 = nullptr;
    if (layer == 0)      { s0 = Whh0 + (size_t)grow * 512; }
    else if (layer == 1) { s0 = Wih1 + (size_t)grow * 512; s1 = Whh1 + (size_t)grow * 512; }
    else                 { s0 = Wih2 + (size_t)grow * 512; s1 = Whh2 + (size_t)grow * 512; }
    {
        int k4 = threadIdx.x;             // 128 threads x 4 = 512
        f32x4 v = *(const f32x4*)&s0[k4 * 4];
        unsigned short o[4];
        #pragma unroll
        for (int j = 0; j < 4; ++j) o[j] = f2b(v[j]);
        *(uint64_t*)&dst[k4 * 4] = *(uint64_t*)o;
    }
    if (s1) {
        int k4 = threadIdx.x;
        f32x4 v = *(const f32x4*)&s1[k4 * 4];
        unsigned short o[4];
        #pragma unroll
        for (int j = 0; j < 4; ++j) o[j] = f2b(v[j]);
        *(uint64_t*)&dst[512 + k4 * 4] = *(uint64_t*)o;
    }
}

// ---------------- build X ----------------
__global__ __launch_bounds__(256) void build_x(
    const float* __restrict__ qf,   // [64][512]
    const float* __restrict__ imf,  // [64][512]
    const int* __restrict__ seq,    // [64][24]
    const float* __restrict__ emb,  // [32000][256]
    unsigned short* __restrict__ X) // [1536][1280] bf16, row m = t*64+b
{
    int r = blockIdx.x;
    int t = r >> 6, b = r & 63;
    int tok = seq[b * 24 + t];
    for (int e = threadIdx.x; e < 1280; e += 256) {
        float v;
        if (e < 256)      v = emb[(size_t)tok * 256 + e];
        else if (e < 768) v = qf[b * 512 + (e - 256)];
        else              v = imf[b * 512 + (e - 768)];
        X[(size_t)r * 1280 + e] = f2b(v);
    }
}

// ---------------- 128x128 MFMA GEMM (G0 pre-pass): C = A @ W^T + b0 + b1 ----
__global__ __launch_bounds__(256) void gemm128(
    const unsigned short* __restrict__ A, int lda,
    const unsigned short* __restrict__ W, int ldb,
    int K,
    const float* __restrict__ bias0,
    const float* __restrict__ bias1,
    float* __restrict__ outf, int ldo, int mblocks, int xcdq)
{
    __shared__ unsigned short lA[128 * 72];
    __shared__ unsigned short lB[128 * 72];
    int lin = blockIdx.x;
    int wg = (lin & 7) * xcdq + (lin >> 3);
    const int m0 = (wg % mblocks) * 128, n0 = (wg / mblocks) * 128;
    const int tid = threadIdx.x;
    const int lane = tid & 63, wid = tid >> 6;
    const int wm = wid >> 1, wn = wid & 1;

    f32x4 acc[4][4] = {};

    for (int kt = 0; kt < K; kt += 64) {
        #pragma unroll
        for (int c = 0; c < 4; ++c) {
            int chunk = tid + c * 256;
            int row = chunk >> 3, kc = (chunk & 7) * 8;
            *(bf16x8*)&lA[row * 72 + kc] =
                *(const bf16x8*)&A[(size_t)(m0 + row) * lda + kt + kc];
            *(bf16x8*)&lB[row * 72 + kc] =
                *(const bf16x8*)&W[(size_t)(n0 + row) * ldb + kt + kc];
        }
        __syncthreads();
        #pragma unroll
        for (int ks = 0; ks < 64; ks += 32) {
            int kl = ks + ((lane >> 4) << 3);
            bf16x8 af[4], bfr[4];
            #pragma unroll
            for (int i = 0; i < 4; ++i)
                af[i] = *(const bf16x8*)&lA[(wm * 64 + i * 16 + (lane & 15)) * 72 + kl];
            #pragma unroll
            for (int j = 0; j < 4; ++j)
                bfr[j] = *(const bf16x8*)&lB[(wn * 64 + j * 16 + (lane & 15)) * 72 + kl];
            #pragma unroll
            for (int i = 0; i < 4; ++i)
                #pragma unroll
                for (int j = 0; j < 4; ++j)
                    acc[i][j] = __builtin_amdgcn_mfma_f32_16x16x32_bf16(
                        af[i], bfr[j], acc[i][j], 0, 0, 0);
        }
        __syncthreads();
    }

    #pragma unroll
    for (int i = 0; i < 4; ++i) {
        #pragma unroll
        for (int j = 0; j < 4; ++j) {
            int n = n0 + wn * 64 + j * 16 + (lane & 15);
            float bias = bias0[n] + bias1[n];
            #pragma unroll
            for (int r = 0; r < 4; ++r) {
                int m = m0 + wm * 64 + i * 16 + ((lane >> 4) << 2) + r;
                outf[(size_t)m * ldo + n] = acc[i][j][r] + bias;
            }
        }
    }
}

// ---- sc0 sc1 (device-coherent, L2-bypass) load/store asm ----
#define ISSUE_CHUNK(buf, kb0)                                                 \
    {                                                                         \
        _Pragma("unroll")                                                     \
        for (int u_ = 0; u_ < 8; ++u_) {                                      \
            int kg_ = (kb0) + u_ * 32 + lk;                                   \
            const unsigned short* ap_ = (kg_ < 512)                           \
                ? &A0[arow + kg_] : &A1[arow + kg_ - 512];                    \
            asm volatile("global_load_dwordx4 %0, %1, off sc0 sc1"            \
                         : "=v"(buf[u_]) : "v"(ap_) : "memory");              \
        }                                                                     \
    }
#define MFMA_CHUNK(buf, kb0)                                                  \
    {                                                                         \
        _Pragma("unroll")                                                     \
        for (int u_ = 0; u_ < 8; ++u_) {                                      \
            int ksl_ = (kb0) + u_ * 32 + lk;                                  \
            _Pragma("unroll")                                                 \
            for (int q_ = 0; q_ < 4; ++q_) {                                  \
                int gx_ = ((ksl_ >> 3) ^ (lrow & 7)) << 3;                    \
                bf16x8 bq_ = *(const bf16x8*)&lb[(q_ * 16 + lrow) * K + gx_]; \
                acc[q_] = __builtin_amdgcn_mfma_f32_16x16x32_bf16(            \
                    buf[u_], bq_, acc[q_], 0, 0, 0);                          \
            }                                                                 \
        }                                                                     \
    }
#define VM_WAIT8 { asm volatile("s_waitcnt vmcnt(8)" ::: "memory");           \
                   __builtin_amdgcn_sched_barrier(0); }
#define VM_WAIT0 { asm volatile("s_waitcnt vmcnt(0)" ::: "memory");           \
                   __builtin_amdgcn_sched_barrier(0); }

// ---------------- fused persistent kernel: LSTM wavefront + fc consumers ----
__global__ __launch_bounds__(256, 1) void fused_wave(
    const unsigned short* __restrict__ Wpk,
    const float* __restrict__ G0,            // [24][64][2048]
    const float* __restrict__ bih1, const float* __restrict__ bhh1,
    const float* __restrict__ bih2, const float* __restrict__ bhh2,
    unsigned short* __restrict__ hst,        // [3][25][64][512]
    unsigned int* __restrict__ flags,        // [3][24][32]
    const float* __restrict__ fcW,           // [32000][512] f32
    const float* __restrict__ fcb,           // [32000] f32
    float* __restrict__ out)                 // [64][24][32000]
{
    extern __shared__ char smem[];
    const int bid = blockIdx.x;
    const int tid = threadIdx.x;
    const int lane = tid & 63, w = tid >> 6;

    if (bid < NLSTM) {
        // ================= LSTM wavefront path =================
        unsigned short* lb = (unsigned short*)smem;   // [64][K], XOR-swizzled
        const int layer = bid >> 5;
        const int lbid = bid & 31;
        const int j0 = lbid * 16;
        const int lrow = lane & 15, lk = (lane >> 4) * 8;

        const int K = (layer == 0) ? 512 : 1024;
        const size_t wbase = (layer == 0) ? 0
                           : (layer == 1) ? (size_t)32 * 64 * 512
                                          : (size_t)32 * 64 * 512 + (size_t)32 * 64 * 1024;
        const unsigned short* Wblk = Wpk + wbase + (size_t)lbid * 64 * K;

        // ---- stage W once into LDS, granule-XOR swizzled: dst g = src g ^ (row&7)
        {
            const int kshift = (layer == 0) ? 6 : 7;   // log2(K/8)
            const int gm = (K >> 3) - 1;
            const int total = 64 << kshift;
            for (int idx = tid; idx < total; idx += 256) {
                int row = idx >> kshift, g = idx & gm;
                int gx = g ^ (row & 7);
                *(bf16x8*)&lb[row * K + gx * 8] =
                    *(const bf16x8*)&Wblk[(size_t)row * K + g * 8];
            }
        }
        __syncthreads();

        unsigned short* hl = hst + (size_t)layer * 25 * 64 * 512;
        const unsigned short* hlow =
            (layer > 0) ? hst + (size_t)(layer - 1) * 25 * 64 * 512 : nullptr;

        float pb[4] = {0.f, 0.f, 0.f, 0.f};
        if (layer == 1) {
            #pragma unroll
            for (int q = 0; q < 4; ++q)
                pb[q] = bih1[q * 512 + j0 + lrow] + bhh1[q * 512 + j0 + lrow];
        } else if (layer == 2) {
            #pragma unroll
            for (int q = 0; q < 4; ++q)
                pb[q] = bih2[q * 512 + j0 + lrow] + bhh2[q * 512 + j0 + lrow];
        }

        float creg[4] = {0.f, 0.f, 0.f, 0.f};

        for (int t = 0; t < 24; ++t) {
            // ---- G0 prefetch (static data, issue before poll so it overlaps)
            float g0p[16];
            if (layer == 0) {
                const float* gp = G0 + (size_t)t * 64 * 2048;
                #pragma unroll
                for (int r = 0; r < 4; ++r) {
                    int b = w * 16 + ((lane >> 4) << 2) + r;
                    #pragma unroll
                    for (int q = 0; q < 4; ++q)
                        g0p[r * 4 + q] = gp[(size_t)b * 2048 + q * 512 + j0 + lrow];
                }
            }
            // ---- dependency poll: single-writer relaxed flags
            {
                const unsigned int* f1 = nullptr;
                const unsigned int* f2 = nullptr;
                if (layer == 0) {
                    if (t > 0) f1 = flags + (0 * 24 + (t - 1)) * 32;
                } else {
                    f1 = flags + ((layer - 1) * 24 + t) * 32;
                    if (t > 0) f2 = flags + (layer * 24 + (t - 1)) * 32;
                }
                if (w == 0 && f1) {
                    const unsigned int* fp = (lane < 32) ? f1 : (f2 ? f2 : f1);
                    int idx = lane & 31;
                    while (true) {
                        unsigned v = __hip_atomic_load((unsigned int*)&fp[idx],
                                                       __ATOMIC_RELAXED,
                                                       __HIP_MEMORY_SCOPE_AGENT);
                        if (__all(v != 0)) break;
                        __builtin_amdgcn_s_sleep(1);
                    }
                }
            }
            __syncthreads();

            const unsigned short* A0 = (layer == 0)
                ? hl + (size_t)t * 64 * 512
                : hlow + (size_t)(t + 1) * 64 * 512;
            const unsigned short* A1 = (layer == 0)
                ? A0
                : hl + (size_t)t * 64 * 512;

            f32x4 acc[4] = {};
            const int arow = (w * 16 + lrow) * 512;

            bf16x8 bufA[8], bufB[8];
            ISSUE_CHUNK(bufA, 0);
            for (int kb = 0; kb < K; kb += 512) {
                const bool haveB = (kb + 256 < K);
                if (haveB) { ISSUE_CHUNK(bufB, kb + 256); }
                if (haveB) { VM_WAIT8 } else { VM_WAIT0 }
                MFMA_CHUNK(bufA, kb);
                if (kb + 512 < K) { ISSUE_CHUNK(bufA, kb + 512); }
                if (haveB) {
                    if (kb + 512 < K) { VM_WAIT8 } else { VM_WAIT0 }
                    MFMA_CHUNK(bufB, kb + 256);
                }
            }

            // ---- fused LSTM pointwise epilogue; h write-through to L3
            int j = j0 + lrow;
            #pragma unroll
            for (int r = 0; r < 4; ++r) {
                int b = w * 16 + ((lane >> 4) << 2) + r;
                float g[4];
                #pragma unroll
                for (int q = 0; q < 4; ++q) {
                    float p = (layer == 0) ? g0p[r * 4 + q] : pb[q];
                    g[q] = acc[q][r] + p;
                }
                float ig = sigmoidf(g[0]);
                float fg = sigmoidf(g[1]);
                float gg = tanhf(g[2]);
                float og = sigmoidf(g[3]);
                float cn = fg * creg[r] + ig * gg;
                creg[r] = cn;
                float h = og * tanhf(cn);
                unsigned int hb = (unsigned int)f2b(h);
                unsigned short* hp = &hl[((size_t)(t + 1) * 64 + b) * 512 + j];
                asm volatile("global_store_short %0, %1, off sc0 sc1"
                             :: "v"(hp), "v"(hb) : "memory");
            }
            asm volatile("s_waitcnt vmcnt(0)" ::: "memory");
            __syncthreads();
            if (tid == 0) {
                __hip_atomic_store(&flags[(layer * 24 + t) * 32 + lbid], 1u,
                                   __ATOMIC_RELAXED, __HIP_MEMORY_SCOPE_AGENT);
            }
        }
    } else {
        // ================= fc consumer path =================
        // tile g: mt = g/250 (m-tile: rows 128mt.. -> t=2mt,2mt+1), nt = g%250
        unsigned short* lA = (unsigned short*)smem;        // 128*72
        unsigned short* lB = lA + 128 * 72;                // 128*72
        const int f = bid - NLSTM;
        const int wid = w, wm = wid >> 1, wn = wid & 1;
        const unsigned short* h2 = hst + (size_t)2 * 25 * 64 * 512 + 64 * 512;

        int done_mt = -1;
        for (int g = f; g < NTILE; g += FCB) {
            int mt = g / NTILE_N, nt = g % NTILE_N;
            int m0 = mt * 128, n0 = nt * 128;

            if (mt != done_mt) {
                if (tid < 64) {
                    const unsigned int* fb = flags + (2 * 24 + 2 * mt) * 32;
                    while (true) {
                        unsigned v = __hip_atomic_load((unsigned int*)&fb[lane],
                                                       __ATOMIC_RELAXED,
                                                       __HIP_MEMORY_SCOPE_AGENT);
                        if (__all(v != 0)) break;
                        __builtin_amdgcn_s_sleep(4);
                    }
                }
                done_mt = mt;
            }
            __syncthreads();   // poll result visible to all waves; also tile reuse barrier

            f32x4 acc[4][4] = {};

            for (int kt = 0; kt < 512; kt += 64) {
                // A: h2 rows, sc0sc1 (bypass possibly-stale L2), manual waitcnt
                bf16x8 atmp[4];
                #pragma unroll
                for (int c = 0; c < 4; ++c) {
                    int chunk = tid + c * 256;
                    int row = chunk >> 3, kc = (chunk & 7) * 8;
                    const unsigned short* ap = &h2[(size_t)(m0 + row) * 512 + kt + kc];
                    asm volatile("global_load_dwordx4 %0, %1, off sc0 sc1"
                                 : "=v"(atmp[c]) : "v"(ap) : "memory");
                }
                // B: fcW f32 -> bf16 in-staging (normal cached loads)
                #pragma unroll
                for (int c = 0; c < 4; ++c) {
                    int chunk = tid + c * 256;
                    int row = chunk >> 3, kc = (chunk & 7) * 8;
                    const float* bp = &fcW[(size_t)(n0 + row) * 512 + kt + kc];
                    f32x4 v0 = *(const f32x4*)bp;
                    f32x4 v1 = *(const f32x4*)(bp + 4);
                    unsigned short o[8];
                    #pragma unroll
                    for (int x = 0; x < 4; ++x) { o[x] = f2b(v0[x]); o[4 + x] = f2b(v1[x]); }
                    *(bf16x8*)&lB[row * 72 + kc] = *(bf16x8*)o;
                }
                asm volatile("s_waitcnt vmcnt(0)" ::: "memory");
                __builtin_amdgcn_sched_barrier(0);
                #pragma unroll
                for (int c = 0; c < 4; ++c) {
                    int chunk = tid + c * 256;
                    int row = chunk >> 3, kc = (chunk & 7) * 8;
                    *(bf16x8*)&lA[row * 72 + kc] = atmp[c];
                }
                __syncthreads();
                #pragma unroll
                for (int ks = 0; ks < 64; ks += 32) {
                    int kl = ks + ((lane >> 4) << 3);
                    bf16x8 af[4], bfr[4];
                    #pragma unroll
                    for (int i = 0; i < 4; ++i)
                        af[i] = *(const bf16x8*)&lA[(wm * 64 + i * 16 + (lane & 15)) * 72 + kl];
                    #pragma unroll
                    for (int jj = 0; jj < 4; ++jj)
                        bfr[jj] = *(const bf16x8*)&lB[(wn * 64 + jj * 16 + (lane & 15)) * 72 + kl];
                    #pragma unroll
                    for (int i = 0; i < 4; ++i)
                        #pragma unroll
                        for (int jj = 0; jj < 4; ++jj)
                            acc[i][jj] = __builtin_amdgcn_mfma_f32_16x16x32_bf16(
                                af[i], bfr[jj], acc[i][jj], 0, 0, 0);
                }
                __syncthreads();
            }

            #pragma unroll
            for (int i = 0; i < 4; ++i) {
                #pragma unroll
                for (int jj = 0; jj < 4; ++jj) {
                    int n = n0 + wn * 64 + jj * 16 + (lane & 15);
                    float bias = fcb[n];
                    #pragma unroll
                    for (int r = 0; r < 4; ++r) {
                        int m = m0 + wm * 64 + i * 16 + ((lane >> 4) << 2) + r;
                        int b = m & 63, t = m >> 6;
                        out[(size_t)(b * 24 + t) * 32000 + n] = acc[i][jj][r] + bias;
                    }
                }
            }
        }
    }
}

// ---------------- launch ----------------
extern "C" void kernel_launch(void* const* d_in, const int* in_sizes, int n_in,
                              void* d_out, int out_size, void* d_ws, size_t ws_size,
                              hipStream_t stream) {
    const float* qf  = (const float*)d_in[0];
    const float* imf = (const float*)d_in[1];
    const int*   seq = (const int*)d_in[2];
    const float* emb = (const float*)d_in[3];
    // d_in[4..6] dead code
    const float* fcW = (const float*)d_in[7];
    const float* fcb = (const float*)d_in[8];
    const float* Wih[3] = {(const float*)d_in[9],  (const float*)d_in[13], (const float*)d_in[17]};
    const float* Whh[3] = {(const float*)d_in[10], (const float*)d_in[14], (const float*)d_in[18]};
    const float* bih[3] = {(const float*)d_in[11], (const float*)d_in[15], (const float*)d_in[19]};
    const float* bhh[3] = {(const float*)d_in[12], (const float*)d_in[16], (const float*)d_in[20]};

    char* ws = (char*)d_ws;
    unsigned short* X     = (unsigned short*)(ws + 0);          // 3,932,160
    float*          G0    = (float*)(ws + 3932160);             // 12,582,912
    unsigned short* hst   = (unsigned short*)(ws + 16515072);   // 4,915,200
    unsigned int*   flags = (unsigned int*)(ws + 21430272);     // 9,216
    unsigned short* Wpk   = (unsigned short*)(ws + 21440000);   // 10,485,760
    unsigned short* Wih0b = (unsigned short*)(ws + 31925760);   // 5,242,880

    // zero: flags + h slot 0 of each layer
    hipMemsetAsync(flags, 0, 9216, stream);
    for (int l = 0; l < 3; ++l)
        hipMemsetAsync(hst + (size_t)l * 25 * 64 * 512, 0, 64 * 512 * 2, stream);

    { int n4 = 2048 * 1280 / 4;
      cvt_bf16<<<(n4 + 255) / 256, 256, 0, stream>>>(Wih[0], Wih0b, n4); }
    pack_w<<<3 * 32 * 64, 128, 0, stream>>>(Whh[0], Wih[1], Whh[1], Wih[2], Whh[2], Wpk);
    build_x<<<1536, 256, 0, stream>>>(qf, imf, seq, emb, X);

    // G0 = X @ W_ih0^T + b_ih0 + b_hh0 : M=1536, N=2048, K=1280 -> 192 wg
    gemm128<<<192, 256, 0, stream>>>(
        X, 1280, Wih0b, 1280, 1280, bih[0], bhh[0], G0, 2048, 12, 192 / 8);

    // fused persistent kernel: 96 LSTM + 152 fc blocks, 128 KiB dynamic LDS
    fused_wave<<<NLSTM + FCB, 256, 131072, stream>>>(
        Wpk, G0, bih[1], bhh[1], bih[2], bhh[2], hst, flags,
        fcW, fcb, (float*)d_out);
}